// Round 1
// baseline (364.126 us; speedup 1.0000x reference)
//
#include <hip/hip_runtime.h>
#include <stdint.h>

#define NFFT    1024
#define HOP     160
#define NMELS   160
#define SEG     32000
#define PADW    512
#define XLEN    33024            // SEG + 2*PADW
#define NFRAMES 201
#define NBATCH  256
#define NFREQ   256              // bins 0..255 cover all nonzero mel weights
#define TOTFR   (NBATCH * NFRAMES)   // 51456 = 804 * 64 exactly
#define FBW     12               // max nonzero bins per mel row (~8 actual)

using bf16x8 = __attribute__((ext_vector_type(8))) __bf16;
using f32x4  = __attribute__((ext_vector_type(4))) float;

static __device__ __forceinline__ uint16_t f2bf(float f) {
    union { float f; uint32_t u; } v; v.f = f;
    return (uint16_t)((v.u + 0x7FFFu + ((v.u >> 16) & 1u)) >> 16);
}

// ---- prep 1: reflect-pad waveform, convert to bf16:  wp[b][i], i in [0, XLEN)
__global__ void k_pad(const float* __restrict__ wav, uint16_t* __restrict__ wp) {
    int i = blockIdx.x * 256 + threadIdx.x;
    int b = blockIdx.y;
    if (i >= XLEN) return;
    int j = i - PADW;
    j = (j < 0) ? -j : ((j >= SEG) ? (2 * SEG - 2 - j) : j);
    wp[b * XLEN + i] = f2bf(wav[b * SEG + j]);
}

// ---- prep 2: BT[mat][n][k] = bf16(dft[mat][n][k] * window[k]), n<256, k<1024
__global__ void k_bt(const float* __restrict__ dre, const float* __restrict__ dimg,
                     const float* __restrict__ win, uint16_t* __restrict__ BT) {
    int idx = blockIdx.x * 256 + threadIdx.x;     // 2*256*1024 = 524288 total
    int mat = idx >> 18;
    int n   = (idx >> 10) & 255;
    int k   = idx & 1023;
    const float* src = mat ? dimg : dre;
    BT[idx] = f2bf(src[n * 1024 + k] * win[k]);
}

// ---- prep 3: compact sparse mel filterbank rows (contiguous nonzero band)
__global__ void k_fb(const float* __restrict__ fb, int* __restrict__ klo,
                     int* __restrict__ kw, float* __restrict__ fbv) {
    int m = threadIdx.x;
    if (m >= NMELS) return;
    int lo = -1, hi = -1;
    for (int f = 0; f < NFREQ; ++f) {
        float v = fb[m * 513 + f];
        if (v > 0.f) { if (lo < 0) lo = f; hi = f; }
    }
    int w = (lo < 0) ? 0 : (hi - lo + 1);
    if (w > FBW) w = FBW;
    if (lo < 0) lo = 0;
    klo[m] = lo; kw[m] = w;
    for (int j = 0; j < w; ++j) fbv[m * FBW + j] = fb[m * 513 + lo + j];
}

// ---- main: per block, 64 frames x 256 bins power via MFMA, then sparse mel
__global__ __launch_bounds__(512, 4) void k_main(
    const uint16_t* __restrict__ wp, const uint16_t* __restrict__ BT,
    const int* __restrict__ klo, const int* __restrict__ kw,
    const float* __restrict__ fbv, float* __restrict__ out)
{
    __shared__ float pw[64][NFREQ + 1];          // +1 pad: conflict-free column reads
    const int tid  = threadIdx.x;
    const int lane = tid & 63;
    const int wave = tid >> 6;                   // 8 waves: 2 (M) x 4 (N)
    const int wm = wave >> 2, wn = wave & 3;
    const int l15 = lane & 15, lg = lane >> 4;
    const int gBase = blockIdx.x * 64;

    // A fragment base pointers: row = frame, contiguous k (hop overlap in wp)
    const uint16_t* aptr[2];
    #pragma unroll
    for (int mi = 0; mi < 2; ++mi) {
        int g = gBase + wm * 32 + mi * 16 + l15;     // global frame index
        int b = g / NFRAMES;
        int t = g - b * NFRAMES;
        aptr[mi] = wp + b * XLEN + t * HOP + lg * 8;
    }
    // B fragment base pointers: row = freq bin, contiguous k (window folded in)
    const uint16_t* bptrR[4];
    const uint16_t* bptrI[4];
    #pragma unroll
    for (int ni = 0; ni < 4; ++ni) {
        int n = wn * 64 + ni * 16 + l15;
        bptrR[ni] = BT + n * 1024 + lg * 8;
        bptrI[ni] = BT + (NFREQ * 1024) + n * 1024 + lg * 8;
    }

    f32x4 accR[2][4], accI[2][4];
    #pragma unroll
    for (int mi = 0; mi < 2; ++mi)
        #pragma unroll
        for (int ni = 0; ni < 4; ++ni) {
            accR[mi][ni] = f32x4{0.f, 0.f, 0.f, 0.f};
            accI[mi][ni] = f32x4{0.f, 0.f, 0.f, 0.f};
        }

    for (int k0 = 0; k0 < NFFT; k0 += 32) {
        bf16x8 a[2], br[4], bi[4];
        #pragma unroll
        for (int mi = 0; mi < 2; ++mi)
            a[mi] = *reinterpret_cast<const bf16x8*>(aptr[mi] + k0);
        #pragma unroll
        for (int ni = 0; ni < 4; ++ni) {
            br[ni] = *reinterpret_cast<const bf16x8*>(bptrR[ni] + k0);
            bi[ni] = *reinterpret_cast<const bf16x8*>(bptrI[ni] + k0);
        }
        #pragma unroll
        for (int mi = 0; mi < 2; ++mi)
            #pragma unroll
            for (int ni = 0; ni < 4; ++ni) {
                accR[mi][ni] = __builtin_amdgcn_mfma_f32_16x16x32_bf16(
                    a[mi], br[ni], accR[mi][ni], 0, 0, 0);
                accI[mi][ni] = __builtin_amdgcn_mfma_f32_16x16x32_bf16(
                    a[mi], bi[ni], accI[mi][ni], 0, 0, 0);
            }
    }

    // power -> LDS.  C/D layout: col = lane&15, row = (lane>>4)*4 + reg
    #pragma unroll
    for (int mi = 0; mi < 2; ++mi)
        #pragma unroll
        for (int ni = 0; ni < 4; ++ni)
            #pragma unroll
            for (int e = 0; e < 4; ++e) {
                int row = wm * 32 + mi * 16 + lg * 4 + e;
                int col = wn * 64 + ni * 16 + l15;
                float r = accR[mi][ni][e], im = accI[mi][ni][e];
                pw[row][col] = r * r + im * im;
            }
    __syncthreads();

    // sparse mel projection + transposed store  out[b][m][t]
    for (int idx = tid; idx < NMELS * 64; idx += 512) {
        int m  = idx >> 6;
        int ti = idx & 63;
        int g = gBase + ti;
        int b = g / NFRAMES;
        int t = g - b * NFRAMES;
        float acc = 0.f;
        int lo = klo[m], w = kw[m];
        for (int j = 0; j < w; ++j)
            acc += fbv[m * FBW + j] * pw[ti][lo + j];
        out[b * (NMELS * NFRAMES) + m * NFRAMES + t] = acc;
    }
}

extern "C" void kernel_launch(void* const* d_in, const int* in_sizes, int n_in,
                              void* d_out, int out_size, void* d_ws, size_t ws_size,
                              hipStream_t stream) {
    const float* wav  = (const float*)d_in[0];
    const float* win  = (const float*)d_in[1];
    const float* dre  = (const float*)d_in[2];
    const float* dimg = (const float*)d_in[3];
    const float* mfb  = (const float*)d_in[4];
    float* out = (float*)d_out;

    uint8_t* ws = (uint8_t*)d_ws;
    // ws layout (bytes):
    //   [0, 1MB)            BT bf16 [2][256][1024]
    //   [1MB, 1MB+16.9MB)   padded waveform bf16 [256][33024]
    //   then klo[160], kw[160], fbv[160][12]
    uint16_t* BT  = (uint16_t*)ws;
    uint16_t* wp  = (uint16_t*)(ws + (1u << 20));
    size_t off = (1u << 20) + (size_t)NBATCH * XLEN * 2;   // 17,956,864
    int*   klo = (int*)(ws + off);
    int*   kw  = (int*)(ws + off + 640);
    float* fbv = (float*)(ws + off + 1280);

    hipLaunchKernelGGL(k_bt,  dim3(2048),     dim3(256), 0, stream, dre, dimg, win, BT);
    hipLaunchKernelGGL(k_pad, dim3(129, 256), dim3(256), 0, stream, wav, wp);
    hipLaunchKernelGGL(k_fb,  dim3(1),        dim3(192), 0, stream, mfb, klo, kw, fbv);
    hipLaunchKernelGGL(k_main, dim3(TOTFR / 64), dim3(512), 0, stream,
                       wp, BT, klo, kw, fbv, out);
}

// Round 2
// 159.873 us; speedup vs baseline: 2.2776x; 2.2776x over previous
//
#include <hip/hip_runtime.h>
#include <stdint.h>

#define NFFT    1024
#define HOP     160
#define NMELS   160
#define SEG     32000
#define PADW    512
#define XLEN    33024            // SEG + 2*PADW
#define NFRAMES 201
#define NBATCH  256
#define NFREQ   256              // bins 0..255 cover all nonzero mel weights
#define TOTFR   (NBATCH * NFRAMES)   // 51456 = 402 * 128
#define FBW     12
#define BM      128
#define BK      64
#define NSTEP   (NFFT / BK)      // 16

using bf16x8 = __attribute__((ext_vector_type(8))) __bf16;
using f32x4  = __attribute__((ext_vector_type(4))) float;

static __device__ __forceinline__ uint16_t f2bf(float f) {
    union { float f; uint32_t u; } v; v.f = f;
    return (uint16_t)((v.u + 0x7FFFu + ((v.u >> 16) & 1u)) >> 16);
}
static __device__ __forceinline__ float bf2f(uint16_t h) {
    union { uint32_t u; float f; } v; v.u = (uint32_t)h << 16;
    return v.f;
}

// CK-style addrspace casts for global_load_lds (16B per lane, dest = base + lane*16)
static __device__ __forceinline__ void gload16(const void* g, void* l) {
    __builtin_amdgcn_global_load_lds(
        (const __attribute__((address_space(1))) uint32_t*)(uintptr_t)g,
        (__attribute__((address_space(3))) uint32_t*)(uintptr_t)l,
        16, 0, 0);
}

// ---- prep 1: reflect-pad waveform, convert to bf16
__global__ void k_pad(const float* __restrict__ wav, uint16_t* __restrict__ wp) {
    int i = blockIdx.x * 256 + threadIdx.x;
    int b = blockIdx.y;
    if (i >= XLEN) return;
    int j = i - PADW;
    j = (j < 0) ? -j : ((j >= SEG) ? (2 * SEG - 2 - j) : j);
    wp[b * XLEN + i] = f2bf(wav[b * SEG + j]);
}

// ---- prep 2: BT[mat][n][k] = bf16(dft[mat][n][k] * window[k]), n<256, k<1024
__global__ void k_bt(const float* __restrict__ dre, const float* __restrict__ dimg,
                     const float* __restrict__ win, uint16_t* __restrict__ BT) {
    int idx = blockIdx.x * 256 + threadIdx.x;
    int mat = idx >> 18;
    int n   = (idx >> 10) & 255;
    int k   = idx & 1023;
    const float* src = mat ? dimg : dre;
    BT[idx] = f2bf(src[n * 1024 + k] * win[k]);
}

// ---- prep 3: compact sparse mel filterbank rows
__global__ void k_fb(const float* __restrict__ fb, int* __restrict__ klo,
                     int* __restrict__ kw, float* __restrict__ fbv) {
    int m = threadIdx.x;
    if (m >= NMELS) return;
    int lo = -1, hi = -1;
    for (int f = 0; f < NFREQ; ++f) {
        float v = fb[m * 513 + f];
        if (v > 0.f) { if (lo < 0) lo = f; hi = f; }
    }
    int w = (lo < 0) ? 0 : (hi - lo + 1);
    if (w > FBW) w = FBW;
    if (lo < 0) lo = 0;
    klo[m] = lo; kw[m] = w;
    for (int j = 0; j < w; ++j) fbv[m * FBW + j] = fb[m * 513 + lo + j];
}

// ---- main GEMM: 128 frames x 256 bins per block, K=1024, double-buffered LDS
// LDS layout (bytes): [0,16K) A0 | [16K,32K) A1 | [32K,96K) B0 | [96K,160K) B1
// A[128][64] bf16 rows of 128B (8 chunks of 16B), chunk-swizzled: chunk ^= row&7
// B[512][64] bf16 (rows = mat*256+bin), same swizzle.
__global__ __launch_bounds__(512, 2) void k_main(
    const uint16_t* __restrict__ wp, const uint16_t* __restrict__ BT,
    const int* __restrict__ klo, const int* __restrict__ kw,
    const float* __restrict__ fbv, float* __restrict__ out)
{
    __shared__ uint4 smem4[163840 / 16];     // 160 KB
    char* smem = (char*)smem4;

    const int tid  = threadIdx.x;
    const int lane = tid & 63;
    const int wave = tid >> 6;               // 8 waves: 2(M) x 4(N)
    const int wm = wave >> 2, wn = wave & 3;
    const int l15 = lane & 15, lg = lane >> 4;
    const int gBase = blockIdx.x * BM;

    // ---- staging slot precompute: 80 slots of 1KB (8 rows x 128B), 10/wave
    const int lrow8 = lane >> 3;             // row within slot
    const int lchk  = lane & 7;              // chunk position in LDS (linear)
    const int schunk = lchk ^ lrow8;         // inverse-swizzled source chunk
    const uint16_t* srcp[10];
    uint32_t dstoff[10], dststep[10];
    #pragma unroll
    for (int i = 0; i < 10; ++i) {
        int s = wave * 10 + i;
        if (s < 16) {                        // A slots: rows 0..127 (frames)
            int row = s * 8 + lrow8;
            int g = gBase + row;
            int b = g / NFRAMES, t = g - b * NFRAMES;
            srcp[i]   = wp + (size_t)b * XLEN + t * HOP + schunk * 8;
            dstoff[i] = (uint32_t)s * 1024;
            dststep[i] = 16384;
        } else {                             // B slots: rows 0..511
            int r = (s - 16) * 8 + lrow8;
            srcp[i]   = BT + (size_t)r * 1024 + schunk * 8;
            dstoff[i] = 32768u + (uint32_t)(s - 16) * 1024;
            dststep[i] = 65536;
        }
    }

    auto STAGE = [&](int buf, int ks) {
        #pragma unroll
        for (int i = 0; i < 10; ++i)
            gload16(srcp[i] + (size_t)ks * BK,
                    smem + dstoff[i] + (buf ? dststep[i] : 0u));
    };

    f32x4 accR[4][4], accI[4][4];
    #pragma unroll
    for (int mi = 0; mi < 4; ++mi)
        #pragma unroll
        for (int ni = 0; ni < 4; ++ni) {
            accR[mi][ni] = f32x4{0.f, 0.f, 0.f, 0.f};
            accI[mi][ni] = f32x4{0.f, 0.f, 0.f, 0.f};
        }

    STAGE(0, 0);
    for (int ks = 0; ks < NSTEP; ++ks) {
        const int cur = ks & 1;
        if (ks < NSTEP - 1) {
            STAGE(cur ^ 1, ks + 1);
            __builtin_amdgcn_sched_barrier(0);
            asm volatile("s_waitcnt vmcnt(10)" ::: "memory");
        } else {
            __builtin_amdgcn_sched_barrier(0);
            asm volatile("s_waitcnt vmcnt(0)" ::: "memory");
        }
        __builtin_amdgcn_s_barrier();
        __builtin_amdgcn_sched_barrier(0);

        const char* Ac = smem + cur * 16384;
        const char* Bc = smem + 32768 + cur * 65536;
        #pragma unroll
        for (int kh = 0; kh < 2; ++kh) {
            const int swz = ((lg + 4 * kh) ^ (l15 & 7)) * 16;
            bf16x8 a[4], br[4], bi[4];
            #pragma unroll
            for (int mi = 0; mi < 4; ++mi)
                a[mi] = *(const bf16x8*)(Ac + (wm * 64 + mi * 16 + l15) * 128 + swz);
            #pragma unroll
            for (int ni = 0; ni < 4; ++ni) {
                br[ni] = *(const bf16x8*)(Bc + (wn * 64 + ni * 16 + l15) * 128 + swz);
                bi[ni] = *(const bf16x8*)(Bc + 32768 + (wn * 64 + ni * 16 + l15) * 128 + swz);
            }
            #pragma unroll
            for (int mi = 0; mi < 4; ++mi)
                #pragma unroll
                for (int ni = 0; ni < 4; ++ni) {
                    accR[mi][ni] = __builtin_amdgcn_mfma_f32_16x16x32_bf16(
                        a[mi], br[ni], accR[mi][ni], 0, 0, 0);
                    accI[mi][ni] = __builtin_amdgcn_mfma_f32_16x16x32_bf16(
                        a[mi], bi[ni], accI[mi][ni], 0, 0, 0);
                }
        }
        __builtin_amdgcn_sched_barrier(0);
        __builtin_amdgcn_s_barrier();
    }

    // ---- epilogue: power (bf16) into B0 region [128][256], col-swizzled
    uint16_t* pw16 = (uint16_t*)(smem + 32768);
    #pragma unroll
    for (int mi = 0; mi < 4; ++mi)
        #pragma unroll
        for (int ni = 0; ni < 4; ++ni)
            #pragma unroll
            for (int e = 0; e < 4; ++e) {
                int row = wm * 64 + mi * 16 + lg * 4 + e;
                int col = wn * 64 + ni * 16 + l15;
                float r = accR[mi][ni][e], im = accI[mi][ni][e];
                pw16[row * 256 + (col ^ ((row & 31) << 1))] = f2bf(r * r + im * im);
            }
    __syncthreads();

    // ---- sparse mel projection + transposed store out[b][m][t]
    for (int idx = tid; idx < NMELS * BM; idx += 512) {
        int m  = idx >> 7;
        int ti = idx & 127;
        int g = gBase + ti;
        int b = g / NFRAMES, t = g - b * NFRAMES;
        int lo = klo[m], w = kw[m];
        int sw = (ti & 31) << 1;
        const uint16_t* prow = pw16 + ti * 256;
        float acc = 0.f;
        for (int j = 0; j < w; ++j)
            acc += fbv[m * FBW + j] * bf2f(prow[(lo + j) ^ sw]);
        out[(size_t)b * (NMELS * NFRAMES) + m * NFRAMES + t] = acc;
    }
}

extern "C" void kernel_launch(void* const* d_in, const int* in_sizes, int n_in,
                              void* d_out, int out_size, void* d_ws, size_t ws_size,
                              hipStream_t stream) {
    const float* wav  = (const float*)d_in[0];
    const float* win  = (const float*)d_in[1];
    const float* dre  = (const float*)d_in[2];
    const float* dimg = (const float*)d_in[3];
    const float* mfb  = (const float*)d_in[4];
    float* out = (float*)d_out;

    uint8_t* ws = (uint8_t*)d_ws;
    uint16_t* BT  = (uint16_t*)ws;                       // 1 MB
    uint16_t* wp  = (uint16_t*)(ws + (1u << 20));        // 16.9 MB
    size_t off = (1u << 20) + (size_t)NBATCH * XLEN * 2;
    int*   klo = (int*)(ws + off);
    int*   kw  = (int*)(ws + off + 640);
    float* fbv = (float*)(ws + off + 1280);

    hipLaunchKernelGGL(k_bt,  dim3(2048),     dim3(256), 0, stream, dre, dimg, win, BT);
    hipLaunchKernelGGL(k_pad, dim3(129, 256), dim3(256), 0, stream, wav, wp);
    hipLaunchKernelGGL(k_fb,  dim3(1),        dim3(192), 0, stream, mfb, klo, kw, fbv);
    hipLaunchKernelGGL(k_main, dim3(TOTFR / BM), dim3(512), 0, stream,
                       wp, BT, klo, kw, fbv, out);
}